// Round 17
// baseline (452.492 us; speedup 1.0000x reference)
//
#include <hip/hip_runtime.h>
#include <hip/hip_bf16.h>
#include <cstdint>
#include <cstddef>

typedef short short8 __attribute__((ext_vector_type(8)));
typedef float f32x4 __attribute__((ext_vector_type(4)));
typedef float f32x16 __attribute__((ext_vector_type(16)));
typedef unsigned short u16x4 __attribute__((ext_vector_type(4)));

__device__ inline unsigned short f2b(float f) {
    union { __hip_bfloat16 h; unsigned short u; } cv;
    cv.h = __float2bfloat16(f);
    return cv.u;
}
__device__ inline float b2f(unsigned short u) {
    union { __hip_bfloat16 h; unsigned short u; } cv;
    cv.u = u;
    return __bfloat162float(cv.h);
}
__device__ inline float prelu(float v, float a) { return v >= 0.f ? v : a * v; }

// ---------------------------------------------------------------------------
// Prep: transpose+cast weights. (unchanged)
// ---------------------------------------------------------------------------
__global__ void k_prep(const float* __restrict__ cw1,
                       const float* __restrict__ cw2,
                       const float* __restrict__ cw3,
                       const float* __restrict__ fw1,
                       const float* __restrict__ fw2,
                       unsigned short* __restrict__ cw1e,
                       unsigned short* __restrict__ cw2bf,
                       unsigned short* __restrict__ cw3bf,
                       unsigned short* __restrict__ fw1hi,
                       unsigned short* __restrict__ fw1lo,
                       float* __restrict__ fw2t)
{
    const int i = blockIdx.x * 256 + threadIdx.x;
    const int stride = gridDim.x * 256;
    if (i < 1024) {
        const int oc = i >> 5, k = i & 31;
        float v = 0.f;
        if (k < 27) { const int tap = k / 3, c = k - 3 * tap; v = cw1[oc * 27 + c * 9 + tap]; }
        cw1e[i] = f2b(v);
    }
    if (i < 18432) {
        const int tap = i >> 11, r = i & 2047, oc = r >> 5, ic = r & 31;
        cw2bf[i] = f2b(cw2[oc * 288 + ic * 9 + tap]);
    }
    for (int j = i; j < 204800; j += stride) {
        const int tap = j >> 13, r = j & 8191, oc = r >> 6, ic = r & 63;
        cw3bf[j] = f2b(cw3[oc * 1600 + ic * 25 + tap]);
    }
    for (int j = i; j < 524288; j += stride) {
        const int oc = j >> 11, k = j & 2047;
        const float w = fw1[j];
        const unsigned short hi = f2b(w);
        const unsigned short lo = f2b(w - b2f(hi));
        const size_t o = ((size_t)(k >> 3) * 256 + oc) * 8 + (k & 7);
        fw1hi[o] = hi; fw1lo[o] = lo;
    }
    for (int j = i; j < 32768; j += stride) {
        const int k = j >> 7, oc = j & 127;
        fw2t[j] = fw2[oc * 256 + k];
    }
}

// ---------------------------------------------------------------------------
// Conv stack: 2 batches per block, 256 threads = 4 waves. (r12 base)
// conv1: bitmask B-build, slot-major padded h1p epilogue (r12 verbatim).
// conv2: 32x32x16, sequential row-strips with unroll(disable) so the two
//        strips' register scopes stay SEPARATE (r16's unroll merged them ->
//        176 VGPR, 1 block/CU). Target ~80 VGPR concurrent in conv2.
// conv3: r12 verbatim (32x32x16, wave = 32 oc x 128 pos).
// LDS ~40.4 KB -> 2 blocks/CU.
// ---------------------------------------------------------------------------
__global__ __launch_bounds__(256) void k_convstack(
    const float* __restrict__ x,
    const unsigned short* __restrict__ cw1e, const float* __restrict__ cb1, const float* __restrict__ a1p,
    const unsigned short* __restrict__ cw2bf, const float* __restrict__ cb2, const float* __restrict__ a2p,
    const unsigned short* __restrict__ cw3bf, const float* __restrict__ cb3, const float* __restrict__ a3p,
    unsigned short* __restrict__ h3out)
{
    const int b0 = blockIdx.x * 2;
    const int t = threadIdx.x;
    const int wv = t >> 6;        // wave 0..3
    const int l  = t & 63;        // lane
    const int lx = l & 15;
    const int q  = l >> 4;        // 0..3

    __shared__ unsigned char  clsp[1156];            //  1.2 KB (border=255)
    __shared__ unsigned short h1p[4 * 18 * 18 * 8];  // 20.25 KB [slot][18][18][8ic], zero borders
    __shared__ unsigned short h2p[2][64 * 72];       // 18 KB  [pos8][ic64 pad72]
    int* hist = (int*)(&h2p[1][0]);                  // 4 KB overlay on h2p[1] bytes [0,4096)
    unsigned* umask = (unsigned*)(&h2p[1][2048]);    // 4 KB overlay on h2p[1] bytes [4096,8192)

    const float a1 = *a1p, a2 = *a2p, a3 = *a3p;

    // ---- phase 0: zero h1p once (borders persist; interior overwritten) ----
    for (int i = t; i < 5184; i += 256) ((unsigned int*)h1p)[i] = 0u;

    #pragma clang loop unroll(disable)
    for (int half = 0; half < 2; ++half) {
        const int b = b0 + half;

        // ---- init hist + clsp ----
        for (int i = t; i < 1024; i += 256) hist[i] = 0;
        for (int i = t; i < 1156; i += 256) clsp[i] = 255;
        __syncthreads();

        // ---- histogram (exact int counts) ----
        const float* xb = x + (size_t)b * 2048;
        for (int n = t; n < 1024; n += 256) {
            const float iv = xb[n];
            const float qv = xb[1024 + n];
            if (iv >= -2.f && iv <= 2.f && qv >= -2.f && qv <= 2.f) {
                int ii = (int)floorf((iv + 2.f) * 8.f);
                int qq = (int)floorf((qv + 2.f) * 8.f);
                ii = ii < 0 ? 0 : (ii > 31 ? 31 : ii);
                qq = qq < 0 ? 0 : (qq > 31 ? 31 : qq);
                atomicAdd(&hist[ii * 32 + qq], 1);
            }
        }
        __syncthreads();

        // ---- class map [high,med,low] -> 0/1/2 ----
        for (int i = t; i < 1024; i += 256) {
            const int H = hist[i];
            clsp[(i >> 5) * 34 + (i & 31) + 35] = (H > 15) ? 0 : ((H > 5) ? 1 : 2);
        }
        __syncthreads();

        // ---- per-position 27-bit one-hot bitmask (hist now dead) ----
        for (int i = t; i < 1024; i += 256) {
            const int y = i >> 5, xx = i & 31;
            unsigned m = 0;
            #pragma unroll
            for (int tap = 0; tap < 9; ++tap) {
                const int ky = tap / 3, kx = tap % 3;
                const unsigned c = clsp[(y + ky) * 34 + (xx + kx)];
                if (c < 3u) m |= 1u << (tap * 3 + c);
            }
            umask[i] = m;
        }
        __syncthreads();

        // ======== conv1: one-hot MFMA via bitmask B-build (r12) ========
        {
            const int mt = wv & 1;        // oc half
            const int yh = wv >> 1;       // y half
            const short8 a1f = *(const short8*)(cw1e + (mt * 16 + lx) * 32 + q * 8);
            float b1r[4];
            #pragma unroll
            for (int r = 0; r < 4; ++r) b1r[r] = cb1[mt * 16 + q * 4 + r];

            for (int py = yh * 8; py < yh * 8 + 8; ++py) {
                f32x4 mac[4];
                #pragma unroll
                for (int d = 0; d < 4; ++d) {
                    const int y = 2 * py + (d >> 1);
                    const int xx = (d & 1) * 16 + lx;
                    const unsigned m = umask[y * 32 + xx];
                    short8 bf;
                    #pragma unroll
                    for (int j = 0; j < 8; ++j) {
                        const int k = q * 8 + j;
                        bf[j] = ((m >> k) & 1u) ? (short)0x3F80 : (short)0;
                    }
                    f32x4 z = {0.f, 0.f, 0.f, 0.f};
                    mac[d] = __builtin_amdgcn_mfma_f32_16x16x32_bf16(a1f, bf, z, 0, 0, 0);
                }
                #pragma unroll
                for (int hx = 0; hx < 2; ++hx) {
                    f32x4 u;
                    #pragma unroll
                    for (int r = 0; r < 4; ++r) {
                        float v0 = prelu(mac[hx][r] + b1r[r], a1);
                        float v1 = prelu(mac[2 + hx][r] + b1r[r], a1);
                        u[r] = v0 + v1;
                    }
                    #pragma unroll
                    for (int r = 0; r < 4; ++r) u[r] += __shfl_xor(u[r], 1);
                    if ((lx & 1) == 0) {
                        const int px = hx * 8 + (lx >> 1);
                        const int slot = mt * 2 + (q >> 1);   // ic slot = (mt*16+q*4)/8
                        u16x4 pk;
                        #pragma unroll
                        for (int r = 0; r < 4; ++r) pk[r] = f2b(0.25f * u[r]);
                        *(u16x4*)(h1p + slot * 2592 + ((py + 1) * 18 + (px + 1)) * 8 + (q & 1) * 4) = pk;
                    }
                }
            }
        }
        __syncthreads();

        // ======== conv2: 32x32x16, sequential row-strips (NOT unrolled) ====
        // strip nt: D[64 oc][32 pos], pos (y0 = (wv*2+nt)*2 + (col>>4), x0 = col&15).
        // k = kk*16 + hi*8 + j -> ic; ic-slot = kk*2 + hi.
        // tap (ky,kx) reads padded (y0+ky, x0+kx): base (y0*18+x0), imm adds tap.
        {
            const int col = l & 31;
            const int hi  = l >> 5;
            const unsigned short* abase2 = cw2bf + col * 32 + hi * 8;

            #pragma clang loop unroll(disable)
            for (int nt = 0; nt < 2; ++nt) {
                const int y0 = (wv * 2 + nt) * 2 + (col >> 4);   // conv row 0..15
                const int x0 = col & 15;
                const char* bbase = (const char*)h1p + hi * 5184 + (y0 * 18 + x0) * 16;

                f32x16 acc0, acc1;
                #pragma unroll
                for (int r = 0; r < 16; ++r) { acc0[r] = 0.f; acc1[r] = 0.f; }

                short8 aC[2][2], aN[2][2];
                #pragma unroll
                for (int mt = 0; mt < 2; ++mt)
                    #pragma unroll
                    for (int kk = 0; kk < 2; ++kk)
                        aC[mt][kk] = *(const short8*)(abase2 + mt * 1024 + kk * 16);

                #pragma unroll
                for (int tap = 0; tap < 9; ++tap) {
                    if (tap < 8) {
                        const unsigned short* anext = abase2 + (tap + 1) * 2048;
                        #pragma unroll
                        for (int mt = 0; mt < 2; ++mt)
                            #pragma unroll
                            for (int kk = 0; kk < 2; ++kk)
                                aN[mt][kk] = *(const short8*)(anext + mt * 1024 + kk * 16);
                    }
                    const int ky = tap / 3, kx = tap % 3;
                    const int imm = (ky * 18 + kx) * 16;
                    #pragma unroll
                    for (int kk = 0; kk < 2; ++kk) {
                        const short8 bf = *(const short8*)(bbase + kk * 10368 + imm);
                        acc0 = __builtin_amdgcn_mfma_f32_32x32x16_bf16(aC[0][kk], bf, acc0, 0, 0, 0);
                        acc1 = __builtin_amdgcn_mfma_f32_32x32x16_bf16(aC[1][kk], bf, acc1, 0, 0, 0);
                    }
                    #pragma unroll
                    for (int mt = 0; mt < 2; ++mt)
                        #pragma unroll
                        for (int kk = 0; kk < 2; ++kk) aC[mt][kk] = aN[mt][kk];
                }

                // epilogue: bias + prelu + pool (row pair col^16, col pair col^1)
                #pragma unroll
                for (int mt = 0; mt < 2; ++mt) {
                    f32x16 u;
                    #pragma unroll
                    for (int r = 0; r < 16; ++r) {
                        const float bb2 = cb2[mt * 32 + (r & 3) + 8 * (r >> 2) + 4 * hi];
                        u[r] = prelu((mt == 0 ? acc0[r] : acc1[r]) + bb2, a2);
                    }
                    #pragma unroll
                    for (int r = 0; r < 16; ++r) u[r] += __shfl_xor(u[r], 16);
                    #pragma unroll
                    for (int r = 0; r < 16; ++r) u[r] += __shfl_xor(u[r], 1);
                    if ((col & 17) == 0) {
                        const int py = wv * 2 + nt;          // pooled row 0..7
                        const int px = (col & 15) >> 1;      // pooled col 0..7
                        const int pos = py * 8 + px;
                        #pragma unroll
                        for (int g4 = 0; g4 < 4; ++g4) {
                            u16x4 pk;
                            #pragma unroll
                            for (int r = 0; r < 4; ++r) pk[r] = f2b(0.25f * u[g4 * 4 + r]);
                            *(u16x4*)(&h2p[half][pos * 72 + mt * 32 + 8 * g4 + 4 * hi]) = pk;
                        }
                    }
                }
            }
        }
        __syncthreads();
    }

    // ======== conv3: 32x32x16, wave = 32 oc x 128 pos (r12 verbatim) ====
    {
        const int col = l & 31;
        const int hi  = l >> 5;

        f32x16 acc[4];
        #pragma unroll
        for (int nt = 0; nt < 4; ++nt)
            #pragma unroll
            for (int r = 0; r < 16; ++r) acc[nt][r] = 0.f;

        const unsigned short* abase = cw3bf + (size_t)(wv * 32 + col) * 64 + hi * 8;

        short8 aC[4], aN[4];
        #pragma unroll
        for (int kk = 0; kk < 4; ++kk)
            aC[kk] = *(const short8*)(abase + kk * 16);

        for (int tap = 0; tap < 25; ++tap) {
            if (tap < 24) {
                const unsigned short* anext = abase + (tap + 1) * 8192;
                #pragma unroll
                for (int kk = 0; kk < 4; ++kk)
                    aN[kk] = *(const short8*)(anext + kk * 16);
            }
            const int ky = (tap * 13) >> 6;        // tap/5
            const int kx = tap - 5 * ky;
            #pragma unroll
            for (int nt = 0; nt < 4; ++nt) {
                const int bb  = nt >> 1;
                const int pos = (nt & 1) * 32 + col;
                const int sy  = (pos >> 3) + ky - 2;
                const int sx  = (pos & 7) + kx - 2;
                const bool ok = (unsigned)sy < 8u && (unsigned)sx < 8u;
                const int soff = (sy * 8 + sx) * 72 + hi * 8;
                #pragma unroll
                for (int kk = 0; kk < 4; ++kk) {
                    short8 bf = {0, 0, 0, 0, 0, 0, 0, 0};
                    if (ok) bf = *(const short8*)(&h2p[bb][soff + kk * 16]);
                    acc[nt] = __builtin_amdgcn_mfma_f32_32x32x16_bf16(aC[kk], bf, acc[nt], 0, 0, 0);
                }
            }
            #pragma unroll
            for (int kk = 0; kk < 4; ++kk) aC[kk] = aN[kk];
        }

        // epilogue: bias + prelu + 2x2 pool (col^1, col^8) + global store
        float b3r[16];
        #pragma unroll
        for (int r = 0; r < 16; ++r)
            b3r[r] = cb3[wv * 32 + (r & 3) + 8 * (r >> 2) + 4 * hi];

        #pragma unroll
        for (int nt = 0; nt < 4; ++nt) {
            f32x16 u;
            #pragma unroll
            for (int r = 0; r < 16; ++r) u[r] = prelu(acc[nt][r] + b3r[r], a3);
            #pragma unroll
            for (int r = 0; r < 16; ++r) u[r] += __shfl_xor(u[r], 1);
            #pragma unroll
            for (int r = 0; r < 16; ++r) u[r] += __shfl_xor(u[r], 8);
            if ((col & 9) == 0) {
                const int b  = b0 + (nt >> 1);
                const int oy = (nt & 1) * 2 + (col >> 4);
                const int ox = (col & 7) >> 1;
                #pragma unroll
                for (int r = 0; r < 16; ++r) {
                    const int oc = wv * 32 + (r & 3) + 8 * (r >> 2) + 4 * hi;
                    h3out[(size_t)b * 2048 + oc * 16 + oy * 4 + ox] = f2b(0.25f * u[r]);
                }
            }
        }
    }
}

// ---------------------------------------------------------------------------
// FC via MFMA (unchanged)
// ---------------------------------------------------------------------------
__global__ __launch_bounds__(512) void k_fc(
    const unsigned short* __restrict__ fw1hi,
    const unsigned short* __restrict__ fw1lo,
    const unsigned short* __restrict__ h3,
    const float* __restrict__ fb1, const float* __restrict__ a4p,
    const float* __restrict__ fw2t, const float* __restrict__ fb2,
    float* __restrict__ out)
{
    const int t  = threadIdx.x;
    const int wv = t >> 6;
    const int l  = t & 63;
    const int lx = l & 15;
    const int q  = l >> 4;
    const int b0 = blockIdx.x * 32;

    __shared__ unsigned short Bs[32 * 128];
    __shared__ float fT[256 * 34];

    f32x4 acc[2][2];
    #pragma unroll
    for (int mt = 0; mt < 2; ++mt)
        #pragma unroll
        for (int bn = 0; bn < 2; ++bn) { f32x4 z = {0.f,0.f,0.f,0.f}; acc[mt][bn] = z; }

    const int srow  = t >> 4;
    const int scolb = (t & 15) << 4;
    const unsigned short* gsrc = h3 + (size_t)(b0 + srow) * 2048
                               + ((scolb ^ ((srow & 7) << 4)) >> 1);

    for (int kc = 0; kc < 2048; kc += 128) {
        __builtin_amdgcn_global_load_lds(
            (const __attribute__((address_space(1))) unsigned int*)(gsrc + kc),
            (__attribute__((address_space(3))) unsigned int*)(Bs + t * 8),
            16, 0, 0);
        __syncthreads();

        #pragma unroll
        for (int s = 0; s < 4; ++s) {
            const int kb = ((kc + s * 32) >> 3) + q;
            const short8 ah0 = *(const short8*)(fw1hi + ((size_t)kb * 256 + wv * 32 + lx) * 8);
            const short8 ah1 = *(const short8*)(fw1hi + ((size_t)kb * 256 + wv * 32 + 16 + lx) * 8);
            const short8 al0 = *(const short8*)(fw1lo + ((size_t)kb * 256 + wv * 32 + lx) * 8);
            const short8 al1 = *(const short8*)(fw1lo + ((size_t)kb * 256 + wv * 32 + 16 + lx) * 8);
            #pragma unroll
            for (int bn = 0; bn < 2; ++bn) {
                const int rr = bn * 16 + lx;
                const short8 bfr = *(const short8*)((const char*)Bs + rr * 256
                                    + ((s * 64 + q * 16) ^ ((rr & 7) << 4)));
                acc[0][bn] = __builtin_amdgcn_mfma_f32_16x16x32_bf16(ah0, bfr, acc[0][bn], 0, 0, 0);
                acc[1][bn] = __builtin_amdgcn_mfma_f32_16x16x32_bf16(ah1, bfr, acc[1][bn], 0, 0, 0);
                acc[0][bn] = __builtin_amdgcn_mfma_f32_16x16x32_bf16(al0, bfr, acc[0][bn], 0, 0, 0);
                acc[1][bn] = __builtin_amdgcn_mfma_f32_16x16x32_bf16(al1, bfr, acc[1][bn], 0, 0, 0);
            }
        }
        __syncthreads();
    }

    const float a4 = *a4p;
    #pragma unroll
    for (int mt = 0; mt < 2; ++mt) {
        #pragma unroll
        for (int r = 0; r < 4; ++r) {
            const int oc = wv * 32 + mt * 16 + q * 4 + r;
            const float bb2 = fb1[oc];
            #pragma unroll
            for (int bn = 0; bn < 2; ++bn) {
                float v = acc[mt][bn][r] + bb2;
                v = v >= 0.f ? v : a4 * v;
                fT[oc * 34 + bn * 16 + lx] = v;
            }
        }
    }
    __syncthreads();

    {
        const int oc2 = t & 127;
        const int bh  = t >> 7;
        float acc2[8];
        #pragma unroll
        for (int j = 0; j < 8; ++j) acc2[j] = 0.f;
        for (int k = 0; k < 256; ++k) {
            const float w = fw2t[k * 128 + oc2];
            const float* fr = &fT[k * 34 + bh * 8];
            #pragma unroll
            for (int j = 0; j < 8; ++j) acc2[j] += w * fr[j];
        }
        const float bb2 = fb2[oc2];
        #pragma unroll
        for (int j = 0; j < 8; ++j)
            out[(size_t)(b0 + bh * 8 + j) * 128 + oc2] = acc2[j] + bb2;
    }
}

// ---------------------------------------------------------------------------
extern "C" void kernel_launch(void* const* d_in, const int* in_sizes, int n_in,
                              void* d_out, int out_size, void* d_ws, size_t ws_size,
                              hipStream_t stream)
{
    const float* x   = (const float*)d_in[0];
    const float* cw1 = (const float*)d_in[1];
    const float* cb1 = (const float*)d_in[2];
    const float* a1  = (const float*)d_in[3];
    const float* cw2 = (const float*)d_in[4];
    const float* cb2 = (const float*)d_in[5];
    const float* a2  = (const float*)d_in[6];
    const float* cw3 = (const float*)d_in[7];
    const float* cb3 = (const float*)d_in[8];
    const float* a3  = (const float*)d_in[9];
    const float* fw1 = (const float*)d_in[10];
    const float* fb1 = (const float*)d_in[11];
    const float* a4  = (const float*)d_in[12];
    const float* fw2 = (const float*)d_in[13];
    const float* fb2 = (const float*)d_in[14];
    float* out = (float*)d_out;

    unsigned short* cw1e  = (unsigned short*)((char*)d_ws);
    unsigned short* cw2bf = (unsigned short*)((char*)d_ws + 2048);
    unsigned short* cw3bf = (unsigned short*)((char*)d_ws + 38912);
    unsigned short* fw1hi = (unsigned short*)((char*)d_ws + 448512);
    unsigned short* fw1lo = (unsigned short*)((char*)d_ws + 1497088);
    float*          fw2t  = (float*)((char*)d_ws + 2545664);
    unsigned short* h3    = (unsigned short*)((char*)d_ws + 2676736);

    const int B = in_sizes[0] / 2048;

    k_prep<<<800, 256, 0, stream>>>(cw1, cw2, cw3, fw1, fw2,
                                    cw1e, cw2bf, cw3bf, fw1hi, fw1lo, fw2t);
    k_convstack<<<B / 2, 256, 0, stream>>>(x, cw1e, cb1, a1, cw2bf, cb2, a2,
                                           cw3bf, cb3, a3, h3);
    k_fc<<<B / 32, 512, 0, stream>>>(fw1hi, fw1lo, h3, fb1, a4, fw2t, fb2, out);
}

// Round 18
// 281.429 us; speedup vs baseline: 1.6078x; 1.6078x over previous
//
#include <hip/hip_runtime.h>
#include <hip/hip_bf16.h>
#include <cstdint>
#include <cstddef>

typedef short short8 __attribute__((ext_vector_type(8)));
typedef float f32x4 __attribute__((ext_vector_type(4)));
typedef float f32x16 __attribute__((ext_vector_type(16)));
typedef unsigned short u16x4 __attribute__((ext_vector_type(4)));

__device__ inline unsigned short f2b(float f) {
    union { __hip_bfloat16 h; unsigned short u; } cv;
    cv.h = __float2bfloat16(f);
    return cv.u;
}
__device__ inline float b2f(unsigned short u) {
    union { __hip_bfloat16 h; unsigned short u; } cv;
    cv.u = u;
    return __bfloat162float(cv.h);
}
__device__ inline float prelu(float v, float a) { return v >= 0.f ? v : a * v; }

// ---------------------------------------------------------------------------
// Prep: transpose+cast weights.
// ---------------------------------------------------------------------------
__global__ void k_prep(const float* __restrict__ cw1,
                       const float* __restrict__ cw2,
                       const float* __restrict__ cw3,
                       const float* __restrict__ fw1,
                       const float* __restrict__ fw2,
                       unsigned short* __restrict__ cw1e,
                       unsigned short* __restrict__ cw2bf,
                       unsigned short* __restrict__ cw3bf,
                       unsigned short* __restrict__ fw1hi,
                       unsigned short* __restrict__ fw1lo,
                       float* __restrict__ fw2t)
{
    const int i = blockIdx.x * 256 + threadIdx.x;
    const int stride = gridDim.x * 256;
    if (i < 1024) {
        const int oc = i >> 5, k = i & 31;
        float v = 0.f;
        if (k < 27) { const int tap = k / 3, c = k - 3 * tap; v = cw1[oc * 27 + c * 9 + tap]; }
        cw1e[i] = f2b(v);
    }
    if (i < 18432) {
        const int tap = i >> 11, r = i & 2047, oc = r >> 5, ic = r & 31;
        cw2bf[i] = f2b(cw2[oc * 288 + ic * 9 + tap]);
    }
    for (int j = i; j < 204800; j += stride) {
        const int tap = j >> 13, r = j & 8191, oc = r >> 6, ic = r & 63;
        cw3bf[j] = f2b(cw3[oc * 1600 + ic * 25 + tap]);
    }
    for (int j = i; j < 524288; j += stride) {
        const int oc = j >> 11, k = j & 2047;
        const float w = fw1[j];
        const unsigned short hi = f2b(w);
        const unsigned short lo = f2b(w - b2f(hi));
        const size_t o = ((size_t)(k >> 3) * 256 + oc) * 8 + (k & 7);
        fw1hi[o] = hi; fw1lo[o] = lo;
    }
    for (int j = i; j < 32768; j += stride) {
        const int k = j >> 7, oc = j & 127;
        fw2t[j] = fw2[oc * 256 + k];
    }
}

// ---------------------------------------------------------------------------
// Conv stack: 2 batches per block, 256 threads = 4 waves. (r12 verified best)
// conv1: bitmask B-build, slot-major padded h1p epilogue.
// conv2: zero-padded h1p [4 slot][18][18][8ic], imm-offset ds_read_b128,
//        a2f[9] small-register weights.
// conv3: 32x32x16, wave = 32 oc x 128 pos, aC/aN[4] prefetch.
// LDS ~40.4 KB -> 2 blocks/CU. VGPR 108.
// ---------------------------------------------------------------------------
__global__ __launch_bounds__(256) void k_convstack(
    const float* __restrict__ x,
    const unsigned short* __restrict__ cw1e, const float* __restrict__ cb1, const float* __restrict__ a1p,
    const unsigned short* __restrict__ cw2bf, const float* __restrict__ cb2, const float* __restrict__ a2p,
    const unsigned short* __restrict__ cw3bf, const float* __restrict__ cb3, const float* __restrict__ a3p,
    unsigned short* __restrict__ h3out)
{
    const int b0 = blockIdx.x * 2;
    const int t = threadIdx.x;
    const int wv = t >> 6;        // wave 0..3
    const int l  = t & 63;        // lane
    const int lx = l & 15;
    const int q  = l >> 4;        // 0..3

    __shared__ unsigned char  clsp[1156];            //  1.2 KB (border=255)
    __shared__ unsigned short h1p[4 * 18 * 18 * 8];  // 20.25 KB [slot][18][18][8ic], zero borders
    __shared__ unsigned short h2p[2][64 * 72];       // 18 KB  [pos8][ic64 pad72]
    int* hist = (int*)(&h2p[1][0]);                  // 4 KB overlay on h2p[1] bytes [0,4096)
    unsigned* umask = (unsigned*)(&h2p[1][2048]);    // 4 KB overlay on h2p[1] bytes [4096,8192)

    const float a1 = *a1p, a2 = *a2p, a3 = *a3p;

    // ---- phase 0: zero h1p once (borders persist; interior overwritten) ----
    for (int i = t; i < 5184; i += 256) ((unsigned int*)h1p)[i] = 0u;

    for (int half = 0; half < 2; ++half) {
        const int b = b0 + half;

        // ---- init hist + clsp ----
        for (int i = t; i < 1024; i += 256) hist[i] = 0;
        for (int i = t; i < 1156; i += 256) clsp[i] = 255;
        __syncthreads();

        // ---- histogram (exact int counts) ----
        const float* xb = x + (size_t)b * 2048;
        for (int n = t; n < 1024; n += 256) {
            const float iv = xb[n];
            const float qv = xb[1024 + n];
            if (iv >= -2.f && iv <= 2.f && qv >= -2.f && qv <= 2.f) {
                int ii = (int)floorf((iv + 2.f) * 8.f);
                int qq = (int)floorf((qv + 2.f) * 8.f);
                ii = ii < 0 ? 0 : (ii > 31 ? 31 : ii);
                qq = qq < 0 ? 0 : (qq > 31 ? 31 : qq);
                atomicAdd(&hist[ii * 32 + qq], 1);
            }
        }
        __syncthreads();

        // ---- class map [high,med,low] -> 0/1/2 ----
        for (int i = t; i < 1024; i += 256) {
            const int H = hist[i];
            clsp[(i >> 5) * 34 + (i & 31) + 35] = (H > 15) ? 0 : ((H > 5) ? 1 : 2);
        }
        __syncthreads();

        // ---- per-position 27-bit one-hot bitmask (hist now dead) ----
        for (int i = t; i < 1024; i += 256) {
            const int y = i >> 5, xx = i & 31;
            unsigned m = 0;
            #pragma unroll
            for (int tap = 0; tap < 9; ++tap) {
                const int ky = tap / 3, kx = tap % 3;
                const unsigned c = clsp[(y + ky) * 34 + (xx + kx)];
                if (c < 3u) m |= 1u << (tap * 3 + c);
            }
            umask[i] = m;
        }
        __syncthreads();

        // ======== conv1: one-hot MFMA via bitmask B-build ========
        {
            const int mt = wv & 1;        // oc half
            const int yh = wv >> 1;       // y half
            const short8 a1f = *(const short8*)(cw1e + (mt * 16 + lx) * 32 + q * 8);
            float b1r[4];
            #pragma unroll
            for (int r = 0; r < 4; ++r) b1r[r] = cb1[mt * 16 + q * 4 + r];

            for (int py = yh * 8; py < yh * 8 + 8; ++py) {
                f32x4 mac[4];
                #pragma unroll
                for (int d = 0; d < 4; ++d) {
                    const int y = 2 * py + (d >> 1);
                    const int xx = (d & 1) * 16 + lx;
                    const unsigned m = umask[y * 32 + xx];
                    short8 bf;
                    #pragma unroll
                    for (int j = 0; j < 8; ++j) {
                        const int k = q * 8 + j;
                        bf[j] = ((m >> k) & 1u) ? (short)0x3F80 : (short)0;
                    }
                    f32x4 z = {0.f, 0.f, 0.f, 0.f};
                    mac[d] = __builtin_amdgcn_mfma_f32_16x16x32_bf16(a1f, bf, z, 0, 0, 0);
                }
                #pragma unroll
                for (int hx = 0; hx < 2; ++hx) {
                    f32x4 u;
                    #pragma unroll
                    for (int r = 0; r < 4; ++r) {
                        float v0 = prelu(mac[hx][r] + b1r[r], a1);
                        float v1 = prelu(mac[2 + hx][r] + b1r[r], a1);
                        u[r] = v0 + v1;
                    }
                    #pragma unroll
                    for (int r = 0; r < 4; ++r) u[r] += __shfl_xor(u[r], 1);
                    if ((lx & 1) == 0) {
                        const int px = hx * 8 + (lx >> 1);
                        const int slot = mt * 2 + (q >> 1);   // ic slot = (mt*16+q*4)/8
                        u16x4 pk;
                        #pragma unroll
                        for (int r = 0; r < 4; ++r) pk[r] = f2b(0.25f * u[r]);
                        *(u16x4*)(h1p + slot * 2592 + ((py + 1) * 18 + (px + 1)) * 8 + (q & 1) * 4) = pk;
                    }
                }
            }
        }
        __syncthreads();

        // ======== conv2: padded imm-offset reads, a2f[9] ========
        {
            short8 a2f[9];
            #pragma unroll
            for (int tap = 0; tap < 9; ++tap)
                a2f[tap] = *(const short8*)(cw2bf + tap * 2048 + (wv * 16 + lx) * 32 + q * 8);
            float b2r[4];
            #pragma unroll
            for (int r = 0; r < 4; ++r) b2r[r] = cb2[wv * 16 + q * 4 + r];

            for (int py = 0; py < 8; ++py) {
                f32x4 acc0 = {0.f, 0.f, 0.f, 0.f}, acc1 = {0.f, 0.f, 0.f, 0.f};
                // padded row for (dy=0,ky=0) is 2py+0; col for kx=0 is lx.
                const char* base0 = (const char*)h1p + q * 5184 + (2 * py * 18 + lx) * 16;
                const char* base1 = base0 + 288;   // +1 row (dy=1)
                #pragma unroll
                for (int tap = 0; tap < 9; ++tap) {
                    const int ky = tap / 3, kx = tap % 3;
                    const int imm = (ky * 18 + kx) * 16;
                    const short8 bf0 = *(const short8*)(base0 + imm);
                    acc0 = __builtin_amdgcn_mfma_f32_16x16x32_bf16(a2f[tap], bf0, acc0, 0, 0, 0);
                    const short8 bf1 = *(const short8*)(base1 + imm);
                    acc1 = __builtin_amdgcn_mfma_f32_16x16x32_bf16(a2f[tap], bf1, acc1, 0, 0, 0);
                }
                f32x4 u;
                #pragma unroll
                for (int r = 0; r < 4; ++r) {
                    float v0 = prelu(acc0[r] + b2r[r], a2);
                    float v1 = prelu(acc1[r] + b2r[r], a2);
                    u[r] = v0 + v1;
                }
                #pragma unroll
                for (int r = 0; r < 4; ++r) u[r] += __shfl_xor(u[r], 1);
                if ((lx & 1) == 0) {
                    const int pos = py * 8 + (lx >> 1);
                    u16x4 pk;
                    #pragma unroll
                    for (int r = 0; r < 4; ++r) pk[r] = f2b(0.25f * u[r]);
                    *(u16x4*)(&h2p[half][pos * 72 + wv * 16 + q * 4]) = pk;
                }
            }
        }
        __syncthreads();
    }

    // ======== conv3: 32x32x16, wave = 32 oc x 128 pos ====
    {
        const int col = l & 31;
        const int hi  = l >> 5;

        f32x16 acc[4];
        #pragma unroll
        for (int nt = 0; nt < 4; ++nt)
            #pragma unroll
            for (int r = 0; r < 16; ++r) acc[nt][r] = 0.f;

        const unsigned short* abase = cw3bf + (size_t)(wv * 32 + col) * 64 + hi * 8;

        short8 aC[4], aN[4];
        #pragma unroll
        for (int kk = 0; kk < 4; ++kk)
            aC[kk] = *(const short8*)(abase + kk * 16);

        for (int tap = 0; tap < 25; ++tap) {
            if (tap < 24) {
                const unsigned short* anext = abase + (tap + 1) * 8192;
                #pragma unroll
                for (int kk = 0; kk < 4; ++kk)
                    aN[kk] = *(const short8*)(anext + kk * 16);
            }
            const int ky = (tap * 13) >> 6;        // tap/5
            const int kx = tap - 5 * ky;
            #pragma unroll
            for (int nt = 0; nt < 4; ++nt) {
                const int bb  = nt >> 1;
                const int pos = (nt & 1) * 32 + col;
                const int sy  = (pos >> 3) + ky - 2;
                const int sx  = (pos & 7) + kx - 2;
                const bool ok = (unsigned)sy < 8u && (unsigned)sx < 8u;
                const int soff = (sy * 8 + sx) * 72 + hi * 8;
                #pragma unroll
                for (int kk = 0; kk < 4; ++kk) {
                    short8 bf = {0, 0, 0, 0, 0, 0, 0, 0};
                    if (ok) bf = *(const short8*)(&h2p[bb][soff + kk * 16]);
                    acc[nt] = __builtin_amdgcn_mfma_f32_32x32x16_bf16(aC[kk], bf, acc[nt], 0, 0, 0);
                }
            }
            #pragma unroll
            for (int kk = 0; kk < 4; ++kk) aC[kk] = aN[kk];
        }

        // epilogue: bias + prelu + 2x2 pool (col^1, col^8) + global store
        float b3r[16];
        #pragma unroll
        for (int r = 0; r < 16; ++r)
            b3r[r] = cb3[wv * 32 + (r & 3) + 8 * (r >> 2) + 4 * hi];

        #pragma unroll
        for (int nt = 0; nt < 4; ++nt) {
            f32x16 u;
            #pragma unroll
            for (int r = 0; r < 16; ++r) u[r] = prelu(acc[nt][r] + b3r[r], a3);
            #pragma unroll
            for (int r = 0; r < 16; ++r) u[r] += __shfl_xor(u[r], 1);
            #pragma unroll
            for (int r = 0; r < 16; ++r) u[r] += __shfl_xor(u[r], 8);
            if ((col & 9) == 0) {
                const int b  = b0 + (nt >> 1);
                const int oy = (nt & 1) * 2 + (col >> 4);
                const int ox = (col & 7) >> 1;
                #pragma unroll
                for (int r = 0; r < 16; ++r) {
                    const int oc = wv * 32 + (r & 3) + 8 * (r >> 2) + 4 * hi;
                    h3out[(size_t)b * 2048 + oc * 16 + oy * 4 + ox] = f2b(0.25f * u[r]);
                }
            }
        }
    }
}

// ---------------------------------------------------------------------------
// FC via MFMA
// ---------------------------------------------------------------------------
__global__ __launch_bounds__(512) void k_fc(
    const unsigned short* __restrict__ fw1hi,
    const unsigned short* __restrict__ fw1lo,
    const unsigned short* __restrict__ h3,
    const float* __restrict__ fb1, const float* __restrict__ a4p,
    const float* __restrict__ fw2t, const float* __restrict__ fb2,
    float* __restrict__ out)
{
    const int t  = threadIdx.x;
    const int wv = t >> 6;
    const int l  = t & 63;
    const int lx = l & 15;
    const int q  = l >> 4;
    const int b0 = blockIdx.x * 32;

    __shared__ unsigned short Bs[32 * 128];
    __shared__ float fT[256 * 34];

    f32x4 acc[2][2];
    #pragma unroll
    for (int mt = 0; mt < 2; ++mt)
        #pragma unroll
        for (int bn = 0; bn < 2; ++bn) { f32x4 z = {0.f,0.f,0.f,0.f}; acc[mt][bn] = z; }

    const int srow  = t >> 4;
    const int scolb = (t & 15) << 4;
    const unsigned short* gsrc = h3 + (size_t)(b0 + srow) * 2048
                               + ((scolb ^ ((srow & 7) << 4)) >> 1);

    for (int kc = 0; kc < 2048; kc += 128) {
        __builtin_amdgcn_global_load_lds(
            (const __attribute__((address_space(1))) unsigned int*)(gsrc + kc),
            (__attribute__((address_space(3))) unsigned int*)(Bs + t * 8),
            16, 0, 0);
        __syncthreads();

        #pragma unroll
        for (int s = 0; s < 4; ++s) {
            const int kb = ((kc + s * 32) >> 3) + q;
            const short8 ah0 = *(const short8*)(fw1hi + ((size_t)kb * 256 + wv * 32 + lx) * 8);
            const short8 ah1 = *(const short8*)(fw1hi + ((size_t)kb * 256 + wv * 32 + 16 + lx) * 8);
            const short8 al0 = *(const short8*)(fw1lo + ((size_t)kb * 256 + wv * 32 + lx) * 8);
            const short8 al1 = *(const short8*)(fw1lo + ((size_t)kb * 256 + wv * 32 + 16 + lx) * 8);
            #pragma unroll
            for (int bn = 0; bn < 2; ++bn) {
                const int rr = bn * 16 + lx;
                const short8 bfr = *(const short8*)((const char*)Bs + rr * 256
                                    + ((s * 64 + q * 16) ^ ((rr & 7) << 4)));
                acc[0][bn] = __builtin_amdgcn_mfma_f32_16x16x32_bf16(ah0, bfr, acc[0][bn], 0, 0, 0);
                acc[1][bn] = __builtin_amdgcn_mfma_f32_16x16x32_bf16(ah1, bfr, acc[1][bn], 0, 0, 0);
                acc[0][bn] = __builtin_amdgcn_mfma_f32_16x16x32_bf16(al0, bfr, acc[0][bn], 0, 0, 0);
                acc[1][bn] = __builtin_amdgcn_mfma_f32_16x16x32_bf16(al1, bfr, acc[1][bn], 0, 0, 0);
            }
        }
        __syncthreads();
    }

    const float a4 = *a4p;
    #pragma unroll
    for (int mt = 0; mt < 2; ++mt) {
        #pragma unroll
        for (int r = 0; r < 4; ++r) {
            const int oc = wv * 32 + mt * 16 + q * 4 + r;
            const float bb2 = fb1[oc];
            #pragma unroll
            for (int bn = 0; bn < 2; ++bn) {
                float v = acc[mt][bn][r] + bb2;
                v = v >= 0.f ? v : a4 * v;
                fT[oc * 34 + bn * 16 + lx] = v;
            }
        }
    }
    __syncthreads();

    {
        const int oc2 = t & 127;
        const int bh  = t >> 7;
        float acc2[8];
        #pragma unroll
        for (int j = 0; j < 8; ++j) acc2[j] = 0.f;
        for (int k = 0; k < 256; ++k) {
            const float w = fw2t[k * 128 + oc2];
            const float* fr = &fT[k * 34 + bh * 8];
            #pragma unroll
            for (int j = 0; j < 8; ++j) acc2[j] += w * fr[j];
        }
        const float bb2 = fb2[oc2];
        #pragma unroll
        for (int j = 0; j < 8; ++j)
            out[(size_t)(b0 + bh * 8 + j) * 128 + oc2] = acc2[j] + bb2;
    }
}

// ---------------------------------------------------------------------------
extern "C" void kernel_launch(void* const* d_in, const int* in_sizes, int n_in,
                              void* d_out, int out_size, void* d_ws, size_t ws_size,
                              hipStream_t stream)
{
    const float* x   = (const float*)d_in[0];
    const float* cw1 = (const float*)d_in[1];
    const float* cb1 = (const float*)d_in[2];
    const float* a1  = (const float*)d_in[3];
    const float* cw2 = (const float*)d_in[4];
    const float* cb2 = (const float*)d_in[5];
    const float* a2  = (const float*)d_in[6];
    const float* cw3 = (const float*)d_in[7];
    const float* cb3 = (const float*)d_in[8];
    const float* a3  = (const float*)d_in[9];
    const float* fw1 = (const float*)d_in[10];
    const float* fb1 = (const float*)d_in[11];
    const float* a4  = (const float*)d_in[12];
    const float* fw2 = (const float*)d_in[13];
    const float* fb2 = (const float*)d_in[14];
    float* out = (float*)d_out;

    unsigned short* cw1e  = (unsigned short*)((char*)d_ws);
    unsigned short* cw2bf = (unsigned short*)((char*)d_ws + 2048);
    unsigned short* cw3bf = (unsigned short*)((char*)d_ws + 38912);
    unsigned short* fw1hi = (unsigned short*)((char*)d_ws + 448512);
    unsigned short* fw1lo = (unsigned short*)((char*)d_ws + 1497088);
    float*          fw2t  = (float*)((char*)d_ws + 2545664);
    unsigned short* h3    = (unsigned short*)((char*)d_ws + 2676736);

    const int B = in_sizes[0] / 2048;

    k_prep<<<800, 256, 0, stream>>>(cw1, cw2, cw3, fw1, fw2,
                                    cw1e, cw2bf, cw3bf, fw1hi, fw1lo, fw2t);
    k_convstack<<<B / 2, 256, 0, stream>>>(x, cw1e, cb1, a1, cw2bf, cb2, a2,
                                           cw3bf, cb3, a3, h3);
    k_fc<<<B / 32, 512, 0, stream>>>(fw1hi, fw1lo, h3, fb1, a4, fw2t, fb2, out);
}